// Round 5
// baseline (433.836 us; speedup 1.0000x reference)
//
#include <hip/hip_runtime.h>
#include <hip/hip_bf16.h>

// tRNN fused: embedding -> 6 tree levels (MFMA bf16) -> cpr -> softmax
// R5: R3 structure + LDS exactly 32KB (z/partial carved into dead tree bytes)
//     -> 5 blocks/CU at launch_bounds(256,5); bias-in-acc-init; reg-preloaded
//     biases; split K-chains on tail levels. VALU cpr tail (fits in VGPR cap).
// B=8192, SIDES=2, L=64, V=10000, D=128, C=128, R=7

typedef __attribute__((ext_vector_type(8))) short bf16x8;
typedef __attribute__((ext_vector_type(4))) float f32x4;

#define VOCN (10000 * 128)
#define CPSN (128 * 256)
#define CPRN (128 * 256)

__device__ __forceinline__ uint pk2(float a, float b) {
  union { __hip_bfloat162 h2; uint u; } cv;
  cv.h2 = __float22bfloat162_rn(make_float2(a, b));
  return cv.u;
}
__device__ __forceinline__ float2 up2(uint u) {
  union { uint u; __hip_bfloat162 h2; } cv; cv.u = u;
  return __bfloat1622float2(cv.h2);
}
__device__ __forceinline__ float fast_tanh(float x) {
  float e = __builtin_amdgcn_exp2f(x * 2.88539008f);   // exp(2x)
  return 1.0f - 2.0f * __builtin_amdgcn_rcpf(e + 1.0f);
}
__device__ __forceinline__ int slotf(int r) { return r ^ ((r >> 3) & 7); }

// ---- prep: f32 -> bf16 (voc fused with bias) into d_ws ----
__global__ void prep_kernel(const float* __restrict__ voc_w, const float* __restrict__ voc_b,
                            const float* __restrict__ cps_w, const float* __restrict__ cpr_w,
                            ushort* __restrict__ ws) {
  const int i4 = (blockIdx.x * 256 + threadIdx.x) * 4;
  if (i4 >= VOCN + CPSN + CPRN) return;
  float4 v;
  if (i4 < VOCN) {
    v = *(const float4*)(voc_w + i4);
    const float4 bb = *(const float4*)(voc_b + (i4 & 127));
    v.x += bb.x; v.y += bb.y; v.z += bb.z; v.w += bb.w;
  } else if (i4 < VOCN + CPSN) {
    v = *(const float4*)(cps_w + (i4 - VOCN));
  } else {
    v = *(const float4*)(cpr_w + (i4 - VOCN - CPSN));
  }
  uint2 w; w.x = pk2(v.x, v.y); w.y = pk2(v.z, v.w);
  *(uint2*)(ws + i4) = w;
}

// LDS layout per tree (16 KB): elem k of row r at byte (k>>3)*1024 + slot(r)*16 + (k&7)*2
template<int NODES>
__device__ __forceinline__ void level_step(char* hb, const bf16x8 (&A)[2][8],
                                           const f32x4 (&bias)[2],
                                           int l15, int lh, int wv) {
  constexpr int NTOT = 2 * NODES;
  constexpr int NT = (NTOT + 15) / 16;
  constexpr int LOG = NODES == 32 ? 5 : NODES == 16 ? 4 : NODES == 8 ? 3 :
                      NODES == 4 ? 2 : NODES == 2 ? 1 : 0;
  constexpr bool SPLIT = (NT == 1);   // tail levels: 2 independent 4-deep chains
  const f32x4 zero = {0.f, 0.f, 0.f, 0.f};

  f32x4 acc[NT][2];
  f32x4 acc2[SPLIT ? 1 : NT][2];
#pragma unroll
  for (int nt = 0; nt < NT; ++nt) {
    acc[nt][0] = bias[0]; acc[nt][1] = bias[1];
    if constexpr (SPLIT) { acc2[nt][0] = zero; acc2[nt][1] = zero; }
  }

#pragma unroll
  for (int nt = 0; nt < NT; ++nt) {
    int node = nt * 16 + l15;
    if constexpr (NTOT < 16) node = node < NTOT ? node : NTOT - 1;
    const int tree = node >> LOG;
    const int i = node & (NODES - 1);
    const char* tb = hb + tree * 16384 + lh * 1024;
    const int s0 = slotf(2 * i) * 16;
    const int s1 = slotf(2 * i + 1) * 16;
    bf16x8 bl[4], br[4];
#pragma unroll
    for (int q = 0; q < 4; ++q) bl[q] = *(const bf16x8*)(tb + q * 4096 + s0);
#pragma unroll
    for (int q = 0; q < 4; ++q) br[q] = *(const bf16x8*)(tb + q * 4096 + s1);
#pragma unroll
    for (int q = 0; q < 4; ++q) {
      acc[nt][0] = __builtin_amdgcn_mfma_f32_16x16x32_bf16(A[0][q], bl[q], acc[nt][0], 0, 0, 0);
      acc[nt][1] = __builtin_amdgcn_mfma_f32_16x16x32_bf16(A[1][q], bl[q], acc[nt][1], 0, 0, 0);
    }
#pragma unroll
    for (int q = 0; q < 4; ++q) {
      if constexpr (SPLIT) {
        acc2[nt][0] = __builtin_amdgcn_mfma_f32_16x16x32_bf16(A[0][4 + q], br[q], acc2[nt][0], 0, 0, 0);
        acc2[nt][1] = __builtin_amdgcn_mfma_f32_16x16x32_bf16(A[1][4 + q], br[q], acc2[nt][1], 0, 0, 0);
      } else {
        acc[nt][0] = __builtin_amdgcn_mfma_f32_16x16x32_bf16(A[0][4 + q], br[q], acc[nt][0], 0, 0, 0);
        acc[nt][1] = __builtin_amdgcn_mfma_f32_16x16x32_bf16(A[1][4 + q], br[q], acc[nt][1], 0, 0, 0);
      }
    }
  }
  __syncthreads();   // all reads done before overwrite

#pragma unroll
  for (int nt = 0; nt < NT; ++nt) {
    int node = nt * 16 + l15;
    bool valid = true;
    if constexpr (NTOT < 16) { valid = node < NTOT; if (!valid) node = NTOT - 1; }
    const int tree = node >> LOG;
    const int i = node & (NODES - 1);
    char* tw = hb + tree * 16384 + slotf(i) * 16;
#pragma unroll
    for (int mt = 0; mt < 2; ++mt) {
      f32x4 s = acc[nt][mt];
      if constexpr (SPLIT) {
        s[0] += acc2[nt][mt][0]; s[1] += acc2[nt][mt][1];
        s[2] += acc2[nt][mt][2]; s[3] += acc2[nt][mt][3];
      }
      const int d0 = wv * 32 + mt * 16 + lh * 4;
      uint2 w;
      w.x = pk2(fast_tanh(s[0]), fast_tanh(s[1]));
      w.y = pk2(fast_tanh(s[2]), fast_tanh(s[3]));
      if (valid) *(uint2*)(tw + (d0 >> 3) * 1024 + (d0 & 7) * 2) = w;
    }
  }
  __syncthreads();
}

template<int PRE>
__global__ __launch_bounds__(256, 5)
void trnn_kernel(const int* __restrict__ tokens,
                 const float* __restrict__ voc_w, const float* __restrict__ voc_b,
                 const float* __restrict__ cps_w, const float* __restrict__ cps_b,
                 const float* __restrict__ cpr_w, const float* __restrict__ cpr_b,
                 const float* __restrict__ sm_w, const float* __restrict__ sm_b,
                 const ushort* __restrict__ wsb, float* __restrict__ out) {
  __shared__ ushort h[16384];      // exactly 32 KB: 2 trees x (16 chunks x 64 slots x 16B)
  const int tid = threadIdx.x;
  const int lane = tid & 63, wv = tid >> 6;
  const int l15 = lane & 15, lh = lane >> 4;
  const int b = blockIdx.x;
  char* hb = (char*)h;

  const ushort* voc_bf = wsb;
  const ushort* cps_bf = wsb + VOCN;
  const ushort* cpr_bf = wsb + VOCN + CPSN;

  // ---- cps weights -> A fragments; biases -> regs ----
  bf16x8 A[2][8];
  f32x4 bias[2];
#pragma unroll
  for (int mt = 0; mt < 2; ++mt) {
    const int d = wv * 32 + mt * 16 + l15;
#pragma unroll
    for (int kt = 0; kt < 8; ++kt) {
      const int k = kt * 32 + lh * 8;
      if constexpr (PRE) {
        A[mt][kt] = *(const bf16x8*)(cps_bf + d * 256 + k);
      } else {
        const float* p = cps_w + d * 256 + k;
        float4 lo = *(const float4*)p, hi = *(const float4*)(p + 4);
        union { bf16x8 v; uint4 u; } f;
        f.u.x = pk2(lo.x, lo.y); f.u.y = pk2(lo.z, lo.w);
        f.u.z = pk2(hi.x, hi.y); f.u.w = pk2(hi.z, hi.w);
        A[mt][kt] = f.v;
      }
    }
    const float4 bb = *(const float4*)(cps_b + wv * 32 + mt * 16 + lh * 4);
    bias[mt][0] = bb.x; bias[mt][1] = bb.y; bias[mt][2] = bb.z; bias[mt][3] = bb.w;
  }

  // ---- embedding: 2 threads per (tree, leaf) row ----
  {
    const int tree = tid >> 7, lf = (tid >> 1) & 63, half = tid & 1;
    const int tok = tokens[b * 128 + tree * 64 + lf];
    char* tp = hb + tree * 16384 + half * 8192 + slotf(lf) * 16;
    if constexpr (PRE) {
      const ushort* vr = voc_bf + tok * 128 + half * 64;
#pragma unroll
      for (int j = 0; j < 8; ++j) {
        const int c = (j + lf) & 7;                 // rotate -> spread chunks
        *(uint4*)(tp + c * 1024) = *(const uint4*)(vr + c * 8);
      }
    } else {
      const float* vw = voc_w + tok * 128 + half * 64;
      const float* vb = voc_b + half * 64;
#pragma unroll
      for (int j = 0; j < 8; ++j) {
        const int c = (j + lf) & 7;
        float4 v0 = *(const float4*)(vw + c * 8);
        float4 v1 = *(const float4*)(vw + c * 8 + 4);
        float4 q0 = *(const float4*)(vb + c * 8);
        float4 q1 = *(const float4*)(vb + c * 8 + 4);
        uint4 w;
        w.x = pk2(v0.x + q0.x, v0.y + q0.y);
        w.y = pk2(v0.z + q0.z, v0.w + q0.w);
        w.z = pk2(v1.x + q1.x, v1.y + q1.y);
        w.w = pk2(v1.z + q1.z, v1.w + q1.w);
        *(uint4*)(tp + c * 1024) = w;
      }
    }
  }
  __syncthreads();

  // ---- 6 levels: 64 leaves -> root per tree ----
  level_step<32>(hb, A, bias, l15, lh, wv);
  level_step<16>(hb, A, bias, l15, lh, wv);
  level_step<8>(hb, A, bias, l15, lh, wv);
  level_step<4>(hb, A, bias, l15, lh, wv);
  level_step<2>(hb, A, bias, l15, lh, wv);
  level_step<1>(hb, A, bias, l15, lh, wv);

  // After levels: only slot-0 roots (16B at chunk*1024 per tree) are live.
  // Carve: partial[j] (j<256) at tree0 chunk (j>>4), bytes 512+(j&15)*4.
  //        zbuf[i]    (i<128) at tree1 chunk (i>>3), bytes 768+(i&7)*4.

  // ---- cpr: 2 threads per output c (one per tree-half of K) ----
  {
    const int half = tid >> 7, c = tid & 127;
    const char* rp = hb + half * 16384;   // root row, slot 0
    float acc = 0.f;
#pragma unroll 4
    for (int ch = 0; ch < 16; ++ch) {
      uint4 u = *(const uint4*)(rp + ch * 1024);   // broadcast within wave
      float2 e0 = up2(u.x), e1 = up2(u.y), e2 = up2(u.z), e3 = up2(u.w);
      if constexpr (PRE) {
        uint4 wq = *(const uint4*)(cpr_bf + c * 256 + half * 128 + ch * 8);
        float2 w0 = up2(wq.x), w1 = up2(wq.y), w2 = up2(wq.z), w3 = up2(wq.w);
        acc += e0.x * w0.x + e0.y * w0.y + e1.x * w1.x + e1.y * w1.y
             + e2.x * w2.x + e2.y * w2.y + e3.x * w3.x + e3.y * w3.y;
      } else {
        const float* wr = cpr_w + c * 256 + half * 128 + ch * 8;
        float4 w0 = *(const float4*)wr, w1 = *(const float4*)(wr + 4);
        acc += e0.x * w0.x + e0.y * w0.y + e1.x * w0.z + e1.y * w0.w
             + e2.x * w1.x + e2.y * w1.y + e3.x * w1.z + e3.y * w1.w;
      }
    }
    *(float*)(hb + ((tid >> 4) << 10) + 512 + ((tid & 15) << 2)) = acc;
  }
  __syncthreads();
  if (tid < 128) {
    const float p0 = *(const float*)(hb + ((tid >> 4) << 10) + 512 + ((tid & 15) << 2));
    const int j1 = tid + 128;
    const float p1 = *(const float*)(hb + ((j1 >> 4) << 10) + 512 + ((j1 & 15) << 2));
    float z = p0 + p1 + cpr_b[tid];
    z = z > 0.f ? z : 0.01f * z;
    *(float*)(hb + 16384 + ((tid >> 3) << 10) + 768 + ((tid & 7) << 2)) = z;
  }
  __syncthreads();

  // ---- softmax head (wave 0) ----
  if (wv == 0) {
    const int i0 = lane, i1 = 64 + lane;
    const float za = *(const float*)(hb + 16384 + ((i0 >> 3) << 10) + 768 + ((i0 & 7) << 2));
    const float zc = *(const float*)(hb + 16384 + ((i1 >> 3) << 10) + 768 + ((i1 & 7) << 2));
    float p[7];
#pragma unroll
    for (int j = 0; j < 7; ++j)
      p[j] = za * sm_w[j * 128 + lane] + zc * sm_w[j * 128 + 64 + lane];
#pragma unroll
    for (int j = 0; j < 7; ++j) {
      float v = p[j];
#pragma unroll
      for (int off = 32; off >= 1; off >>= 1) v += __shfl_xor(v, off, 64);
      p[j] = v + sm_b[j];
    }
    float mx = p[0];
#pragma unroll
    for (int j = 1; j < 7; ++j) mx = fmaxf(mx, p[j]);
    float e[7], s = 0.f;
#pragma unroll
    for (int j = 0; j < 7; ++j) { e[j] = __expf(p[j] - mx); s += e[j]; }
    const float inv = 1.f / s;
    if (lane == 0) {
#pragma unroll
      for (int j = 0; j < 7; ++j) out[b * 7 + j] = e[j] * inv;
    }
  }
}

extern "C" void kernel_launch(void* const* d_in, const int* in_sizes, int n_in,
                              void* d_out, int out_size, void* d_ws, size_t ws_size,
                              hipStream_t stream) {
  const int*   tokens = (const int*)  d_in[0];
  const float* voc_w  = (const float*)d_in[1];
  const float* voc_b  = (const float*)d_in[2];
  const float* cps_w  = (const float*)d_in[3];
  const float* cps_b  = (const float*)d_in[4];
  const float* cpr_w  = (const float*)d_in[5];
  const float* cpr_b  = (const float*)d_in[6];
  const float* sm_w   = (const float*)d_in[7];
  const float* sm_b   = (const float*)d_in[8];
  float* out = (float*)d_out;

  const int B = in_sizes[0] / 128;                     // 8192
  const size_t need = (size_t)(VOCN + CPSN + CPRN) * sizeof(ushort);

  if (ws_size >= need) {
    ushort* ws = (ushort*)d_ws;
    const int tot4 = (VOCN + CPSN + CPRN) / 4;
    prep_kernel<<<(tot4 + 255) / 256, 256, 0, stream>>>(voc_w, voc_b, cps_w, cpr_w, ws);
    trnn_kernel<1><<<B, 256, 0, stream>>>(tokens, voc_w, voc_b, cps_w, cps_b,
                                          cpr_w, cpr_b, sm_w, sm_b, ws, out);
  } else {
    trnn_kernel<0><<<B, 256, 0, stream>>>(tokens, voc_w, voc_b, cps_w, cps_b,
                                          cpr_w, cpr_b, sm_w, sm_b,
                                          (const ushort*)d_ws, out);
  }
}

// Round 6
// 161.550 us; speedup vs baseline: 2.6855x; 2.6855x over previous
//
#include <hip/hip_runtime.h>
#include <hip/hip_bf16.h>

// tRNN fused: embedding -> 6 tree levels (MFMA bf16) -> cpr -> softmax
// R6: R3 skeleton (256 thr, launch_bounds(256,4), 32KB LDS, no spill) +
//     all level-loop LDS addresses as precomputed per-lane bases with
//     compile-time immediate offsets (zero per-access VALU), bias-in-acc-init,
//     LDS-carved cpr/softmax scratch.
// B=8192, SIDES=2, L=64, V=10000, D=128, C=128, R=7

typedef __attribute__((ext_vector_type(8))) short bf16x8;
typedef __attribute__((ext_vector_type(4))) float f32x4;

#define VOCN (10000 * 128)
#define CPSN (128 * 256)
#define CPRN (128 * 256)

__device__ __forceinline__ uint pk2(float a, float b) {
  union { __hip_bfloat162 h2; uint u; } cv;
  cv.h2 = __float22bfloat162_rn(make_float2(a, b));
  return cv.u;
}
__device__ __forceinline__ float2 up2(uint u) {
  union { uint u; __hip_bfloat162 h2; } cv; cv.u = u;
  return __bfloat1622float2(cv.h2);
}
__device__ __forceinline__ float fast_tanh(float x) {
  float e = __builtin_amdgcn_exp2f(x * 2.88539008f);   // exp(2x)
  return 1.0f - 2.0f * __builtin_amdgcn_rcpf(e + 1.0f);
}
__device__ __forceinline__ int sf(int r) { return r ^ ((r >> 3) & 7); }   // slot swizzle

// ---- prep: f32 -> bf16 (voc fused with bias) into d_ws ----
__global__ void prep_kernel(const float* __restrict__ voc_w, const float* __restrict__ voc_b,
                            const float* __restrict__ cps_w, const float* __restrict__ cpr_w,
                            ushort* __restrict__ ws) {
  const int i4 = (blockIdx.x * 256 + threadIdx.x) * 4;
  if (i4 >= VOCN + CPSN + CPRN) return;
  float4 v;
  if (i4 < VOCN) {
    v = *(const float4*)(voc_w + i4);
    const float4 bb = *(const float4*)(voc_b + (i4 & 127));
    v.x += bb.x; v.y += bb.y; v.z += bb.z; v.w += bb.w;
  } else if (i4 < VOCN + CPSN) {
    v = *(const float4*)(cps_w + (i4 - VOCN));
  } else {
    v = *(const float4*)(cpr_w + (i4 - VOCN - CPSN));
  }
  uint2 w; w.x = pk2(v.x, v.y); w.y = pk2(v.z, v.w);
  *(uint2*)(ws + i4) = w;
}

// LDS layout per tree (16 KB): elem k of row r at byte
//   (k>>3)*1024 + sf(r)*16 + (k&7)*2 ; tree1 at +16384.
// TOFF: compile-time tree offset. RL/RR: per-lane read bases (left/right child).
#define MFMA16(Ax, Bx, Cx) __builtin_amdgcn_mfma_f32_16x16x32_bf16(Ax, Bx, Cx, 0, 0, 0)

template<int TOFF>
__device__ __forceinline__ void tile16(const char* hb, const bf16x8 (&A)[2][8],
                                       int RL, int RR, f32x4& aA, f32x4& aB) {
  bf16x8 bl[4], br[4];
#pragma unroll
  for (int q = 0; q < 4; ++q) {
    bl[q] = *(const bf16x8*)(hb + RL + TOFF + q * 4096);
    br[q] = *(const bf16x8*)(hb + RR + TOFF + q * 4096);
  }
#pragma unroll
  for (int q = 0; q < 4; ++q) {
    aA = MFMA16(A[0][q], bl[q], aA);
    aB = MFMA16(A[1][q], bl[q], aB);
  }
#pragma unroll
  for (int q = 0; q < 4; ++q) {
    aA = MFMA16(A[0][4 + q], br[q], aA);
    aB = MFMA16(A[1][4 + q], br[q], aB);
  }
}

// W: per-lane write base (includes slot + d-chunk + d-byte); mt1 at +2048.
template<int TOFF>
__device__ __forceinline__ void wtile(char* hb, int W, const f32x4& aA, const f32x4& aB) {
  uint2 w0, w1;
  w0.x = pk2(fast_tanh(aA[0]), fast_tanh(aA[1]));
  w0.y = pk2(fast_tanh(aA[2]), fast_tanh(aA[3]));
  w1.x = pk2(fast_tanh(aB[0]), fast_tanh(aB[1]));
  w1.y = pk2(fast_tanh(aB[2]), fast_tanh(aB[3]));
  *(uint2*)(hb + W + TOFF) = w0;
  *(uint2*)(hb + W + TOFF + 2048) = w1;
}

template<int PRE>
__global__ __launch_bounds__(256, 4)
void trnn_kernel(const int* __restrict__ tokens,
                 const float* __restrict__ voc_w, const float* __restrict__ voc_b,
                 const float* __restrict__ cps_w, const float* __restrict__ cps_b,
                 const float* __restrict__ cpr_w, const float* __restrict__ cpr_b,
                 const float* __restrict__ sm_w, const float* __restrict__ sm_b,
                 const ushort* __restrict__ wsb, float* __restrict__ out) {
  __shared__ ushort h[16384];      // exactly 32 KB: 2 trees x (16 chunks x 64 slots x 16B)
  const int tid = threadIdx.x;
  const int lane = tid & 63, wv = tid >> 6;
  const int l15 = lane & 15, lh = lane >> 4;
  const int b = blockIdx.x;
  char* hb = (char*)h;

  const ushort* voc_bf = wsb;
  const ushort* cps_bf = wsb + VOCN;
  const ushort* cpr_bf = wsb + VOCN + CPSN;

  // ---- per-lane LDS address bases (computed once; level loop uses imm offsets) ----
  // reads: pattern a (i=l15: L1 even tiles, L2), pattern b (i=16+l15: L1 odd tiles)
  const int lhb = lh * 1024;
  const int RLa = lhb + sf(2 * l15) * 16;
  const int RRa = lhb + sf(2 * l15 + 1) * 16;
  const int RLb = lhb + sf(2 * l15 + 32) * 16;
  const int RRb = lhb + sf(2 * l15 + 33) * 16;
  // L3..L6: tree baked per lane: tree=(l15>>LOG)&1, i=l15&(N-1)
  const int RL3 = (((l15 >> 3) & 1) << 14) + lhb + sf((l15 & 7) * 2) * 16;
  const int RR3 = (((l15 >> 3) & 1) << 14) + lhb + sf((l15 & 7) * 2 + 1) * 16;
  const int RL4 = (((l15 >> 2) & 1) << 14) + lhb + sf((l15 & 3) * 2) * 16;
  const int RR4 = (((l15 >> 2) & 1) << 14) + lhb + sf((l15 & 3) * 2 + 1) * 16;
  const int RL5 = (((l15 >> 1) & 1) << 14) + lhb + sf((l15 & 1) * 2) * 16;
  const int RR5 = (((l15 >> 1) & 1) << 14) + lhb + sf((l15 & 1) * 2 + 1) * 16;
  const int RL6 = ((l15 & 1) << 14) + lhb;            // sf(0)=0
  const int RR6 = ((l15 & 1) << 14) + lhb + 16;       // sf(1)=1
  // writes: d0 = wv*32 + lh*4 (mt0); mt1 = +16 -> +2048 bytes
  const int dpart = (((wv * 32 + lh * 4) >> 3) << 10) + ((lh & 1) << 3);
  const int Wa = sf(l15) * 16 + dpart;
  const int Wb = sf(l15 + 16) * 16 + dpart;
  const int W3 = (((l15 >> 3) & 1) << 14) + sf(l15 & 7) * 16 + dpart;
  const int W4 = (((l15 >> 2) & 1) << 14) + sf(l15 & 3) * 16 + dpart;
  const int W5 = (((l15 >> 1) & 1) << 14) + sf(l15 & 1) * 16 + dpart;
  const int W6 = ((l15 & 1) << 14) + dpart;

  // ---- cps weights -> A fragments; biases -> regs ----
  bf16x8 A[2][8];
  f32x4 bias[2];
#pragma unroll
  for (int mt = 0; mt < 2; ++mt) {
    const int d = wv * 32 + mt * 16 + l15;
#pragma unroll
    for (int kt = 0; kt < 8; ++kt) {
      const int k = kt * 32 + lh * 8;
      if constexpr (PRE) {
        A[mt][kt] = *(const bf16x8*)(cps_bf + d * 256 + k);
      } else {
        const float* p = cps_w + d * 256 + k;
        float4 lo = *(const float4*)p, hi = *(const float4*)(p + 4);
        union { bf16x8 v; uint4 u; } f;
        f.u.x = pk2(lo.x, lo.y); f.u.y = pk2(lo.z, lo.w);
        f.u.z = pk2(hi.x, hi.y); f.u.w = pk2(hi.z, hi.w);
        A[mt][kt] = f.v;
      }
    }
    const float4 bb = *(const float4*)(cps_b + wv * 32 + mt * 16 + lh * 4);
    bias[mt][0] = bb.x; bias[mt][1] = bb.y; bias[mt][2] = bb.z; bias[mt][3] = bb.w;
  }

  // ---- embedding: 2 threads per (tree, leaf) row; imm-offset LDS writes ----
  {
    const int tree = tid >> 7, lf = (tid >> 1) & 63, half = tid & 1;
    const int tok = tokens[b * 128 + tree * 64 + lf];
    char* tp = hb + tree * 16384 + half * 8192 + sf(lf) * 16;
    if constexpr (PRE) {
      const ushort* vr = voc_bf + tok * 128 + half * 64;
#pragma unroll
      for (int j = 0; j < 8; ++j)
        *(uint4*)(tp + j * 1024) = *(const uint4*)(vr + j * 8);
    } else {
      const float* vw = voc_w + tok * 128 + half * 64;
      const float* vb = voc_b + half * 64;
#pragma unroll
      for (int j = 0; j < 8; ++j) {
        float4 v0 = *(const float4*)(vw + j * 8);
        float4 v1 = *(const float4*)(vw + j * 8 + 4);
        float4 q0 = *(const float4*)(vb + j * 8);
        float4 q1 = *(const float4*)(vb + j * 8 + 4);
        uint4 w;
        w.x = pk2(v0.x + q0.x, v0.y + q0.y);
        w.y = pk2(v0.z + q0.z, v0.w + q0.w);
        w.z = pk2(v1.x + q1.x, v1.y + q1.y);
        w.w = pk2(v1.z + q1.z, v1.w + q1.w);
        *(uint4*)(tp + j * 1024) = w;
      }
    }
  }
  __syncthreads();

  // ---- Level 1: 64 -> 32 nodes/tree (4 tiles) ----
  {
    f32x4 a0 = bias[0], b0 = bias[1], a1 = bias[0], b1 = bias[1];
    f32x4 a2 = bias[0], b2 = bias[1], a3 = bias[0], b3 = bias[1];
    tile16<0>(hb, A, RLa, RRa, a0, b0);
    tile16<0>(hb, A, RLb, RRb, a1, b1);
    tile16<16384>(hb, A, RLa, RRa, a2, b2);
    tile16<16384>(hb, A, RLb, RRb, a3, b3);
    __syncthreads();
    wtile<0>(hb, Wa, a0, b0);
    wtile<0>(hb, Wb, a1, b1);
    wtile<16384>(hb, Wa, a2, b2);
    wtile<16384>(hb, Wb, a3, b3);
    __syncthreads();
  }
  // ---- Level 2: 32 -> 16 (2 tiles) ----
  {
    f32x4 a0 = bias[0], b0 = bias[1], a1 = bias[0], b1 = bias[1];
    tile16<0>(hb, A, RLa, RRa, a0, b0);
    tile16<16384>(hb, A, RLa, RRa, a1, b1);
    __syncthreads();
    wtile<0>(hb, Wa, a0, b0);
    wtile<16384>(hb, Wa, a1, b1);
    __syncthreads();
  }
  // ---- Level 3: 16 -> 8 (1 tile, full) ----
  {
    f32x4 a0 = bias[0], b0 = bias[1];
    tile16<0>(hb, A, RL3, RR3, a0, b0);
    __syncthreads();
    wtile<0>(hb, W3, a0, b0);
    __syncthreads();
  }
  // ---- Level 4: 8 -> 4 (1 tile, 8 valid cols) ----
  {
    f32x4 a0 = bias[0], b0 = bias[1];
    tile16<0>(hb, A, RL4, RR4, a0, b0);
    __syncthreads();
    if (l15 < 8) wtile<0>(hb, W4, a0, b0);
    __syncthreads();
  }
  // ---- Level 5: 4 -> 2 (4 valid cols) ----
  {
    f32x4 a0 = bias[0], b0 = bias[1];
    tile16<0>(hb, A, RL5, RR5, a0, b0);
    __syncthreads();
    if (l15 < 4) wtile<0>(hb, W5, a0, b0);
    __syncthreads();
  }
  // ---- Level 6: 2 -> 1 root (2 valid cols) ----
  {
    f32x4 a0 = bias[0], b0 = bias[1];
    tile16<0>(hb, A, RL6, RR6, a0, b0);
    __syncthreads();
    if (l15 < 2) wtile<0>(hb, W6, a0, b0);
    __syncthreads();
  }

  // After levels: only slot-0 roots (bytes 0..15 of each chunk, per tree) live.
  // Carve: partial[j] (j<256) at tree0 chunk (j>>4), bytes 512+(j&15)*4.
  //        zbuf[i]    (i<128) at tree1 chunk (i>>3), bytes 768+(i&7)*4.

  // ---- cpr: 2 threads per output c (one per tree-half of K) ----
  {
    const int half = tid >> 7, c = tid & 127;
    const char* rp = hb + half * 16384;   // root row, slot 0
    float acc = 0.f;
#pragma unroll 4
    for (int ch = 0; ch < 16; ++ch) {
      uint4 u = *(const uint4*)(rp + ch * 1024);   // broadcast within wave
      float2 e0 = up2(u.x), e1 = up2(u.y), e2 = up2(u.z), e3 = up2(u.w);
      if constexpr (PRE) {
        uint4 wq = *(const uint4*)(cpr_bf + c * 256 + half * 128 + ch * 8);
        float2 w0 = up2(wq.x), w1 = up2(wq.y), w2 = up2(wq.z), w3 = up2(wq.w);
        acc += e0.x * w0.x + e0.y * w0.y + e1.x * w1.x + e1.y * w1.y
             + e2.x * w2.x + e2.y * w2.y + e3.x * w3.x + e3.y * w3.y;
      } else {
        const float* wr = cpr_w + c * 256 + half * 128 + ch * 8;
        float4 w0 = *(const float4*)wr, w1 = *(const float4*)(wr + 4);
        acc += e0.x * w0.x + e0.y * w0.y + e1.x * w0.z + e1.y * w0.w
             + e2.x * w1.x + e2.y * w1.y + e3.x * w1.z + e3.y * w1.w;
      }
    }
    *(float*)(hb + ((tid >> 4) << 10) + 512 + ((tid & 15) << 2)) = acc;
  }
  __syncthreads();
  if (tid < 128) {
    const float p0 = *(const float*)(hb + ((tid >> 4) << 10) + 512 + ((tid & 15) << 2));
    const int j1 = tid + 128;
    const float p1 = *(const float*)(hb + ((j1 >> 4) << 10) + 512 + ((j1 & 15) << 2));
    float z = p0 + p1 + cpr_b[tid];
    z = z > 0.f ? z : 0.01f * z;
    *(float*)(hb + 16384 + ((tid >> 3) << 10) + 768 + ((tid & 7) << 2)) = z;
  }
  __syncthreads();

  // ---- softmax head (wave 0) ----
  if (wv == 0) {
    const int i0 = lane, i1 = 64 + lane;
    const float za = *(const float*)(hb + 16384 + ((i0 >> 3) << 10) + 768 + ((i0 & 7) << 2));
    const float zc = *(const float*)(hb + 16384 + ((i1 >> 3) << 10) + 768 + ((i1 & 7) << 2));
    float p[7];
#pragma unroll
    for (int j = 0; j < 7; ++j)
      p[j] = za * sm_w[j * 128 + lane] + zc * sm_w[j * 128 + 64 + lane];
#pragma unroll
    for (int j = 0; j < 7; ++j) {
      float v = p[j];
#pragma unroll
      for (int off = 32; off >= 1; off >>= 1) v += __shfl_xor(v, off, 64);
      p[j] = v + sm_b[j];
    }
    float mx = p[0];
#pragma unroll
    for (int j = 1; j < 7; ++j) mx = fmaxf(mx, p[j]);
    float e[7], s = 0.f;
#pragma unroll
    for (int j = 0; j < 7; ++j) { e[j] = __expf(p[j] - mx); s += e[j]; }
    const float inv = 1.f / s;
    if (lane == 0) {
#pragma unroll
      for (int j = 0; j < 7; ++j) out[b * 7 + j] = e[j] * inv;
    }
  }
}

extern "C" void kernel_launch(void* const* d_in, const int* in_sizes, int n_in,
                              void* d_out, int out_size, void* d_ws, size_t ws_size,
                              hipStream_t stream) {
  const int*   tokens = (const int*)  d_in[0];
  const float* voc_w  = (const float*)d_in[1];
  const float* voc_b  = (const float*)d_in[2];
  const float* cps_w  = (const float*)d_in[3];
  const float* cps_b  = (const float*)d_in[4];
  const float* cpr_w  = (const float*)d_in[5];
  const float* cpr_b  = (const float*)d_in[6];
  const float* sm_w   = (const float*)d_in[7];
  const float* sm_b   = (const float*)d_in[8];
  float* out = (float*)d_out;

  const int B = in_sizes[0] / 128;                     // 8192
  const size_t need = (size_t)(VOCN + CPSN + CPRN) * sizeof(ushort);

  if (ws_size >= need) {
    ushort* ws = (ushort*)d_ws;
    const int tot4 = (VOCN + CPSN + CPRN) / 4;
    prep_kernel<<<(tot4 + 255) / 256, 256, 0, stream>>>(voc_w, voc_b, cps_w, cpr_w, ws);
    trnn_kernel<1><<<B, 256, 0, stream>>>(tokens, voc_w, voc_b, cps_w, cps_b,
                                          cpr_w, cpr_b, sm_w, sm_b, ws, out);
  } else {
    trnn_kernel<0><<<B, 256, 0, stream>>>(tokens, voc_w, voc_b, cps_w, cps_b,
                                          cpr_w, cpr_b, sm_w, sm_b,
                                          (const ushort*)d_ws, out);
  }
}